// Round 1
// baseline (674.808 us; speedup 1.0000x reference)
//
#include <hip/hip_runtime.h>
#include <hip/hip_bf16.h>
#include <math.h>

#define B_SZ 1024
#define H_SZ 200
#define E_SZ 256
#define R_SZ 256
#define LN_EPS 1e-5f
#define NEG_HUGE -3.0e38f

typedef short bf16x8 __attribute__((ext_vector_type(8)));
typedef float f32x4 __attribute__((ext_vector_type(4)));

static __device__ inline short f2bf(float f) {
  union { float f; unsigned int u; } v; v.f = f;
  unsigned int u = v.u;
  unsigned int r = (u + 0x7fffu + ((u >> 16) & 1u)) >> 16;  // RNE
  return (short)(unsigned short)r;
}

// mask may arrive as 1-byte bool or promoted int32; flag picked at runtime.
static __device__ inline float mask_at(const void* m, size_t idx, int is_b8) {
  if (is_b8) return ((const unsigned char*)m)[idx] ? 1.f : 0.f;
  return ((const int*)m)[idx] ? 1.f : 0.f;
}

// ---------------- K0: detect mask element width ----------------------------
// byte-mask (p=0.8): ~3277 nonzero bytes in first 4096; int32-mask: ~819.
__global__ void detect_mask_kernel(const unsigned char* __restrict__ mask,
                                   int* __restrict__ flag) {
  __shared__ int cnt;
  if (threadIdx.x == 0) cnt = 0;
  __syncthreads();
  int c = 0;
  for (int i = threadIdx.x; i < 4096; i += 256) c += mask[i] ? 1 : 0;
  atomicAdd(&cnt, c);
  __syncthreads();
  if (threadIdx.x == 0) *flag = (cnt > 2048) ? 1 : 0;
}

// ---------------- K1: q_repr = e_emb @ W_q^T  (B x 256, K=256, fp32) --------
__global__ __launch_bounds__(256) void qrepr_kernel(
    const float* __restrict__ e_emb, const float* __restrict__ Wq,
    float* __restrict__ q_out) {
  __shared__ float emb[4][E_SZ];
  const int t = threadIdx.x;
  const int b0 = blockIdx.x * 4;
  for (int r = 0; r < 4; ++r) emb[r][t] = e_emb[(size_t)(b0 + r) * E_SZ + t];
  __syncthreads();
  float acc[4] = {0.f, 0.f, 0.f, 0.f};
  const float4* wrow = (const float4*)(Wq + (size_t)t * E_SZ);
  for (int k4 = 0; k4 < E_SZ / 4; ++k4) {
    float4 w = wrow[k4];
    const int k = k4 * 4;
#pragma unroll
    for (int r = 0; r < 4; ++r)
      acc[r] += emb[r][k] * w.x + emb[r][k + 1] * w.y + emb[r][k + 2] * w.z +
                emb[r][k + 3] * w.w;
  }
  for (int r = 0; r < 4; ++r) q_out[(size_t)(b0 + r) * E_SZ + t] = acc[r];
}

// ---------------- K2: fused messages GEMM + decay + online softmax + PNA ----
// one block per 4 batch rows (sequential); 512 threads = 8 waves.
// waves: rh = w>>2 (row half of 32-row h-tile), cg = w&3 (64-col group)
#define AGG_LDS_BYTES 152576

__global__ __launch_bounds__(512, 2) void agg_kernel(
    const float* __restrict__ rel, const float* __restrict__ ent,
    const int* __restrict__ htime, const int* __restrict__ qtime,
    const void* __restrict__ mask, const int* __restrict__ mflag,
    const float* __restrict__ Wrel, const float* __restrict__ qws,
    const float* __restrict__ e_emb, const float* __restrict__ log_gamma,
    float* __restrict__ comb) {
  extern __shared__ char smem[];
  short* Wsw = (short*)smem;                    //      0 .. 131072
  short* Asw = (short*)(smem + 131072);         // 131072 .. 147456
  float* q_s = (float*)(smem + 147456);
  float* attn_acc = (float*)(smem + 148480);
  float* mean_b = (float*)(smem + 149504);
  float* max_b = (float*)(smem + 150528);
  float* s_part = (float*)(smem + 151552);
  float* decay_s = (float*)(smem + 152064);
  float* maskf_s = (float*)(smem + 152192);
  float* p_s = (float*)(smem + 152320);
  float* scal = (float*)(smem + 152448);        // {m, l, alpha, nv}

  const int t = threadIdx.x;
  const int lane = t & 63;
  const int w = t >> 6;
  const int rh = w >> 2;
  const int cg = w & 3;
  const int q4 = lane >> 4;
  const int cl = lane & 15;
  const float gamma = expf(log_gamma[0]);
  const int is_b8 = *mflag;

  // ---- stage W_rel once per block, pre-swizzled into B-fragment order ----
  // B-frag semantics: B[k][n], n = lane&15 (=e%16), k = (lane>>4)*8 + j
  for (int pass = 0; pass < 16; ++pass) {
    const int idx = pass * 512 + t;
    const int e = idx >> 5;          // 0..255
    const int rc = idx & 31;         // 8-wide r-chunk
    const float4* src = (const float4*)(Wrel + (size_t)e * R_SZ + rc * 8);
    float4 a0 = src[0], a1 = src[1];
    const int ks = rc >> 2;
    const int lidx = ((rc & 3) << 4) | (e & 15);
    const int csub = e >> 4;
    bf16x8 v;
    v[0] = f2bf(a0.x); v[1] = f2bf(a0.y); v[2] = f2bf(a0.z); v[3] = f2bf(a0.w);
    v[4] = f2bf(a1.x); v[5] = f2bf(a1.y); v[6] = f2bf(a1.z); v[7] = f2bf(a1.w);
    *(bf16x8*)(Wsw + (((csub * 8 + ks) * 64 + lidx) << 3)) = v;
  }

  for (int bi = 0; bi < 4; ++bi) {
    const int b = blockIdx.x + 256 * bi;
    if (t < 256) { attn_acc[t] = 0.f; q_s[t] = qws[(size_t)b * E_SZ + t]; }
    if (t == 0) { scal[0] = NEG_HUGE; scal[1] = 0.f; scal[2] = 0.f; scal[3] = 0.f; }
    float mean4[4] = {0.f, 0.f, 0.f, 0.f};
    float max4[4] = {NEG_HUGE, NEG_HUGE, NEG_HUGE, NEG_HUGE};
    const float qtf = (float)qtime[b];
    __syncthreads();  // also covers W staging on first iteration

    for (int tile = 0; tile < 7; ++tile) {
      const int h0 = tile * 32;
      // ---- stage A tile (32 rows x 256 r) into A-fragment order ----
      {
        const int row = t >> 4;         // 0..31
        const int rcc = t & 15;         // 16-wide r-chunk
        const int h = h0 + row;
        bf16x8 v0 = {}; bf16x8 v1 = {};
        if (h < H_SZ) {
          const float4* src =
              (const float4*)(rel + ((size_t)b * H_SZ + h) * R_SZ + rcc * 16);
          float4 a0 = src[0], a1 = src[1], a2 = src[2], a3 = src[3];
          v0[0] = f2bf(a0.x); v0[1] = f2bf(a0.y); v0[2] = f2bf(a0.z); v0[3] = f2bf(a0.w);
          v0[4] = f2bf(a1.x); v0[5] = f2bf(a1.y); v0[6] = f2bf(a1.z); v0[7] = f2bf(a1.w);
          v1[0] = f2bf(a2.x); v1[1] = f2bf(a2.y); v1[2] = f2bf(a2.z); v1[3] = f2bf(a2.w);
          v1[4] = f2bf(a3.x); v1[5] = f2bf(a3.y); v1[6] = f2bf(a3.z); v1[7] = f2bf(a3.w);
        }
        const int rh2 = row >> 4, rlow = row & 15;
        const int rr0 = rcc * 2, rr1 = rcc * 2 + 1;
        *(bf16x8*)(Asw + (((rh2 * 8 + (rr0 >> 2)) * 64 + (((rr0 & 3) << 4) | rlow)) << 3)) = v0;
        *(bf16x8*)(Asw + (((rh2 * 8 + (rr1 >> 2)) * 64 + (((rr1 & 3) << 4) | rlow)) << 3)) = v1;
      }
      if (t < 32) {
        const int h = h0 + t;
        float mf = 0.f, dc = 0.f;
        if (h < H_SZ) {
          mf = mask_at(mask, (size_t)b * H_SZ + h, is_b8);
          // float-domain subtraction: matches reference exactly, no int32 wrap
          float td = fmaxf(qtf - (float)htime[(size_t)b * H_SZ + h], 0.f);
          dc = expf(-gamma * td);
        }
        maskf_s[t] = mf; decay_s[t] = dc;
      }
      __syncthreads();

      // ---- MFMA: rp[32x256] = relTile(32x256) x Wrel^T(256x256) ----
      f32x4 acc[4] = {};
      for (int ks = 0; ks < 8; ++ks) {
        bf16x8 av = *(bf16x8*)(Asw + (((rh * 8 + ks) * 64 + lane) << 3));
#pragma unroll
        for (int sub = 0; sub < 4; ++sub) {
          bf16x8 bv = *(bf16x8*)(Wsw + ((((cg * 4 + sub) * 8 + ks) * 64 + lane) << 3));
          acc[sub] = __builtin_amdgcn_mfma_f32_16x16x32_bf16(av, bv, acc[sub], 0, 0, 0);
        }
      }

      // ---- epilogue: msg = rp*ent; mean/max partials; score partials ----
      float msgv[16];  // [reg][sub]
      float sc[4];
#pragma unroll
      for (int reg = 0; reg < 4; ++reg) {
        const int row = rh * 16 + q4 * 4 + reg;  // C layout: row=(lane>>4)*4+reg
        const int h = h0 + row;
        const float mf = maskf_s[row];
        const bool realrow = (h < H_SZ);
        float srow = 0.f;
#pragma unroll
        for (int sub = 0; sub < 4; ++sub) {
          const int e = cg * 64 + sub * 16 + cl;  // C layout: col=lane&15
          float entv = realrow ? ent[((size_t)b * H_SZ + h) * E_SZ + e] : 0.f;
          float m = acc[sub][reg] * entv;
          msgv[reg * 4 + sub] = m;
          mean4[sub] += mf * m;
          float cand = realrow ? (mf != 0.f ? m : 0.f) : NEG_HUGE;
          max4[sub] = fmaxf(max4[sub], cand);
          srow += q_s[e] * m;
        }
        sc[reg] = srow;
      }
#pragma unroll
      for (int m = 1; m <= 8; m <<= 1)
#pragma unroll
        for (int reg = 0; reg < 4; ++reg) sc[reg] += __shfl_xor(sc[reg], m, 64);
      if (cl == 0)
#pragma unroll
        for (int reg = 0; reg < 4; ++reg)
          s_part[(rh * 16 + q4 * 4 + reg) * 4 + cg] = sc[reg];
      __syncthreads();

      // ---- online softmax update (wave 0; rows duplicated in lane halves) --
      if (w == 0) {
        const int row = lane & 31;
        const int h = h0 + row;
        float srow = s_part[row * 4] + s_part[row * 4 + 1] +
                     s_part[row * 4 + 2] + s_part[row * 4 + 3];
        float s;
        if (h >= H_SZ) s = NEG_HUGE;
        else if (maskf_s[row] == 0.f) s = -1e9f;
        else s = decay_s[row] * srow * 0.0625f;  // / sqrt(256)
        float mt = s;
#pragma unroll
        for (int m = 1; m <= 16; m <<= 1) mt = fmaxf(mt, __shfl_xor(mt, m, 64));
        const float m_old = scal[0];
        const float m_new = fmaxf(m_old, mt);
        const float alpha = expf(m_old - m_new);
        const float p = expf(s - m_new);
        float lt = p;
#pragma unroll
        for (int m = 1; m <= 16; m <<= 1) lt += __shfl_xor(lt, m, 64);
        if (lane == 0) {
          scal[0] = m_new;
          scal[1] = scal[1] * alpha + lt;
          scal[2] = alpha;
        }
        if (lane < 32) p_s[row] = p;
      }
      __syncthreads();
      {
        const float alpha = scal[2];
        if (t < 256) attn_acc[t] *= alpha;
      }
      __syncthreads();
      // ---- attn accumulation: attn_acc[e] += sum_rows p[row]*msg ----
      float av4[4];
#pragma unroll
      for (int sub = 0; sub < 4; ++sub) {
        float v = 0.f;
#pragma unroll
        for (int reg = 0; reg < 4; ++reg)
          v += p_s[rh * 16 + q4 * 4 + reg] * msgv[reg * 4 + sub];
        v += __shfl_xor(v, 16, 64);
        v += __shfl_xor(v, 32, 64);
        av4[sub] = v;
      }
      if (q4 == 0)
#pragma unroll
        for (int sub = 0; sub < 4; ++sub)
          atomicAdd(&attn_acc[cg * 64 + sub * 16 + cl], av4[sub]);
      __syncthreads();
    }  // tiles

    // ---- per-b finale: reduce mean/max, n_valid, write combined ----
#pragma unroll
    for (int sub = 0; sub < 4; ++sub) {
      float mv = mean4[sub];
      mv += __shfl_xor(mv, 16, 64); mv += __shfl_xor(mv, 32, 64);
      float xv = max4[sub];
      xv = fmaxf(xv, __shfl_xor(xv, 16, 64));
      xv = fmaxf(xv, __shfl_xor(xv, 32, 64));
      mean4[sub] = mv; max4[sub] = xv;
    }
    if (rh == 0 && q4 == 0) {
#pragma unroll
      for (int sub = 0; sub < 4; ++sub) {
        mean_b[cg * 64 + sub * 16 + cl] = mean4[sub];
        max_b[cg * 64 + sub * 16 + cl] = max4[sub];
      }
    }
    if (t < H_SZ) atomicAdd(&scal[3], mask_at(mask, (size_t)b * H_SZ + t, is_b8));
    __syncthreads();
    if (rh == 1 && q4 == 0) {
#pragma unroll
      for (int sub = 0; sub < 4; ++sub) {
        const int e = cg * 64 + sub * 16 + cl;
        mean_b[e] += mean4[sub];
        max_b[e] = fmaxf(max_b[e], max4[sub]);
      }
    }
    __syncthreads();
    if (t < 256) {
      const float nv = fmaxf(scal[3], 1.f);
      const float l = scal[1];
      float* dst = comb + (size_t)b * 1024;
      dst[t] = mean_b[t] / nv;
      dst[256 + t] = max_b[t];
      dst[512 + t] = attn_acc[t] / l;
      dst[768 + t] = e_emb[(size_t)b * E_SZ + t];
    }
    __syncthreads();
  }  // bi
}

// ---------------- K3: GEMM + bias + LayerNorm (+ exact GELU), fp32 ---------
template <int K, int N, bool GELU>
__global__ __launch_bounds__(256) void mlp_kernel(
    const float* __restrict__ X, const float* __restrict__ W,
    const float* __restrict__ bias, const float* __restrict__ lng,
    const float* __restrict__ lnb, float* __restrict__ Y) {
  constexpr int CPT = N / 256;
  __shared__ float xs[4][K];
  __shared__ float pre[4][N];
  __shared__ float red[4][2];
  const int t = threadIdx.x;
  const size_t b0 = (size_t)blockIdx.x * 4;
  for (int r = 0; r < 4; ++r)
    for (int k = t; k < K; k += 256) xs[r][k] = X[(b0 + r) * K + k];
  __syncthreads();
  float acc[4][CPT];
#pragma unroll
  for (int r = 0; r < 4; ++r)
#pragma unroll
    for (int c = 0; c < CPT; ++c) acc[r][c] = 0.f;
  for (int ci = 0; ci < CPT; ++ci) {
    const int c = t + 256 * ci;
    const float4* wr = (const float4*)(W + (size_t)c * K);
    for (int k4 = 0; k4 < K / 4; ++k4) {
      float4 wv = wr[k4];
      const int k = k4 * 4;
#pragma unroll
      for (int r = 0; r < 4; ++r)
        acc[r][ci] += xs[r][k] * wv.x + xs[r][k + 1] * wv.y +
                      xs[r][k + 2] * wv.z + xs[r][k + 3] * wv.w;
    }
  }
  for (int ci = 0; ci < CPT; ++ci) {
    const int c = t + 256 * ci;
#pragma unroll
    for (int r = 0; r < 4; ++r) pre[r][c] = acc[r][ci] + bias[c];
  }
  __syncthreads();
  if (t < 64) {
    const int r = t >> 4, ch = t & 15;
    float s = 0.f, s2 = 0.f;
    for (int i = ch * (N / 16); i < (ch + 1) * (N / 16); ++i) {
      float v = pre[r][i]; s += v; s2 += v * v;
    }
#pragma unroll
    for (int m = 1; m <= 8; m <<= 1) {
      s += __shfl_xor(s, m, 64);
      s2 += __shfl_xor(s2, m, 64);
    }
    if (ch == 0) { red[r][0] = s / N; red[r][1] = s2 / N; }
  }
  __syncthreads();
  for (int ci = 0; ci < CPT; ++ci) {
    const int c = t + 256 * ci;
#pragma unroll
    for (int r = 0; r < 4; ++r) {
      const float mu = red[r][0];
      const float var = fmaxf(red[r][1] - mu * mu, 0.f);
      float x = (pre[r][c] - mu) * rsqrtf(var + LN_EPS) * lng[c] + lnb[c];
      if (GELU) x = 0.5f * x * (1.f + erff(x * 0.70710678118654752f));
      Y[(b0 + r) * N + c] = x;
    }
  }
}

extern "C" void kernel_launch(void* const* d_in, const int* in_sizes, int n_in,
                              void* d_out, int out_size, void* d_ws,
                              size_t ws_size, hipStream_t stream) {
  const float* e_emb = (const float*)d_in[0];
  const float* ent = (const float*)d_in[1];
  const float* rel = (const float*)d_in[2];
  const int* ht = (const int*)d_in[3];
  const int* qt = (const int*)d_in[4];
  const void* mask = d_in[5];  // bool: byte or int32 — detected at runtime
  const float* Wrel = (const float*)d_in[6];
  const float* Wq = (const float*)d_in[7];
  const float* lg = (const float*)d_in[8];
  const float* W1 = (const float*)d_in[9];
  const float* b1 = (const float*)d_in[10];
  const float* ln1g = (const float*)d_in[11];
  const float* ln1b = (const float*)d_in[12];
  const float* W2 = (const float*)d_in[13];
  const float* b2 = (const float*)d_in[14];
  const float* ln2g = (const float*)d_in[15];
  const float* ln2b = (const float*)d_in[16];
  const float* Wc = (const float*)d_in[17];
  const float* bc = (const float*)d_in[18];
  const float* lncg = (const float*)d_in[19];
  const float* lncb = (const float*)d_in[20];

  // Workspace layout (total 6 MB + 4 KB; previous layout needed 7 MB + 4 B and
  // could write past ws_size, corrupting an adjacent input allocation after
  // the first call — matches the "first call right, later calls consistently
  // wrong" post-timing failure):
  //   [0, 4K)            mflag (4 B used)
  //   [4K, 4K+1M)        q_ws   (written by qrepr, read by agg)
  //   [4K, 4K+2M)        t1     (written by mlp1 AFTER agg completes; may
  //                              legally clobber the dead q_ws region)
  //   [4K+2M, 4K+6M)     comb   (written by agg, read by mlp1)
  int* mflag = (int*)d_ws;
  float* q_ws = (float*)((char*)d_ws + 4096);
  float* t1 = (float*)((char*)d_ws + 4096);
  float* comb = (float*)((char*)d_ws + 4096 + (2u << 20));
  float* dyn = (float*)d_out;                          // B x 256
  float* ctx = (float*)d_out + (size_t)B_SZ * E_SZ;    // B x 512

  (void)ws_size;
  (void)hipFuncSetAttribute((const void*)agg_kernel,
                            hipFuncAttributeMaxDynamicSharedMemorySize,
                            AGG_LDS_BYTES);

  detect_mask_kernel<<<1, 256, 0, stream>>>((const unsigned char*)mask, mflag);
  qrepr_kernel<<<256, 256, 0, stream>>>(e_emb, Wq, q_ws);
  agg_kernel<<<256, 512, AGG_LDS_BYTES, stream>>>(rel, ent, ht, qt, mask, mflag,
                                                  Wrel, q_ws, e_emb, lg, comb);
  mlp_kernel<1024, 512, true><<<256, 256, 0, stream>>>(comb, W1, b1, ln1g, ln1b, t1);
  mlp_kernel<512, 256, false><<<256, 256, 0, stream>>>(t1, W2, b2, ln2g, ln2b, dyn);
  mlp_kernel<256, 512, true><<<256, 256, 0, stream>>>(dyn, Wc, bc, lncg, lncb, ctx);
}